// Round 1
// baseline (276.732 us; speedup 1.0000x reference)
//
#include <hip/hip_runtime.h>

// Raindrop forward, MI355X. B=64 T=128 S=64 O=4 E=64 P=16 A=10 OUT=128.
// Key simplifications:
//  - temporal attention collapsed: (Q K^T) W_s = Q (W_s^T K)  -> no TxT matrix
//  - heavy per-(b,t) matmuls (h_map, alpha, 2x propagate) in bf16 MFMA 16x16x32
// ws layout (floats): PE[B*T*16] | bidir[64*64] | masksum[B*64] | adj2num[B*64*64]
// then bytes: WrT bf16 [32][64] | Hh bf16 [B][S][T][64]

typedef unsigned short u16;
typedef unsigned int u32;
typedef __attribute__((ext_vector_type(8))) short short8;
typedef __attribute__((ext_vector_type(4))) float f32x4;

#define OFF_PE    0
#define OFF_BIDIR 131072
#define OFF_MS    135168
#define OFF_ADJ   139264
#define BOFF_WRT  4751360u
#define BOFF_HH   4755456u

__device__ __forceinline__ u16 f2bf(float f){
  union { float f; u32 u; } v; v.f = f;
  u32 u = v.u;
  return (u16)((u + 0x7FFFu + ((u >> 16) & 1u)) >> 16);
}
__device__ __forceinline__ float bf2f(u16 h){
  union { u32 u; float f; } v; v.u = ((u32)h) << 16; return v.f;
}

// ---------------- K0: PE table, bidir, WrT bf16, masksum ----------------
__global__ void k_pre(const float* __restrict__ times, const float* __restrict__ mask,
                      const float* __restrict__ Wb, const float* __restrict__ Wrecv,
                      float* __restrict__ ws_f, u16* __restrict__ wrt) {
  const int blk = blockIdx.x, tid = threadIdx.x;
  if (blk < 32) {                      // PE: (B*T,16) sin|cos
    float* PE = ws_f + OFF_PE;
    #pragma unroll
    for (int r = 0; r < 16; ++r) {
      int id = blk * 4096 + r * 256 + tid;
      int bt = id >> 4, k = id & 15;
      float tv = times[bt];
      int kk = k & 7;
      float fr = expf(-(float)kk * 1.1512925465f); // ln(1e4)/8
      float ang = tv * fr;
      PE[id] = (k < 8) ? sinf(ang) : cosf(ang);
    }
  } else if (blk == 32) {              // bidir = Wb @ Wb^T
    float* bidir = ws_f + OFF_BIDIR;
    for (int r = 0; r < 16; ++r) {
      int idx = r * 256 + tid;
      int i = idx >> 6, j = idx & 63;
      float acc = 0.f;
      for (int e = 0; e < 64; ++e) acc += Wb[i*64+e] * Wb[j*64+e];
      bidir[idx] = acc;
    }
  } else if (blk == 33) {              // WrT[d][e] = W_recv[e][d], pad d 26..31 = 0
    for (int r = 0; r < 8; ++r) {
      int idx = r * 256 + tid;
      int d = idx >> 6, e = idx & 63;
      wrt[idx] = (d < 26) ? f2bf(Wrecv[e*26 + d]) : (u16)0;
    }
  } else {                             // masksum[b][i] = sum_t mask
    int b = blk - 34;
    if (tid < 64) {
      float s = 0.f;
      for (int t = 0; t < 128; ++t) s += mask[(b*128 + t)*64 + tid];
      (ws_f + OFF_MS)[b*64 + tid] = s;
    }
  }
}

// ---------------- K1: adj2 numerator (sum_t alpha) ----------------
__global__ __launch_bounds__(256)
void k_adj(const float* __restrict__ x, const float* __restrict__ mask,
           const float* __restrict__ Wobs, const float* __restrict__ battn,
           const float* __restrict__ brecv, float* __restrict__ ws_f,
           const u16* __restrict__ wrt) {
  __shared__ float xs[64][4];
  __shared__ float maskv[64];
  __shared__ float peL[16];
  __shared__ float brecvL[32];
  __shared__ __align__(16) u16 hA[64][72];
  __shared__ __align__(16) u16 hmA[64][40];
  __shared__ __align__(16) u16 catB[64][40];
  __shared__ __align__(16) u16 wrtL[32][72];

  const int tid = threadIdx.x;
  const int b = blockIdx.y, tc = blockIdx.x;
  const int w = tid >> 6, l = tid & 63, lr = l & 15, lq = l >> 4, kb = lq * 8;
  const int arow = 16 * w + lr;
  const float* PE = ws_f + OFF_PE;
  float* adj = ws_f + OFF_ADJ;

  if (tid < 32) brecvL[tid] = (tid < 26) ? brecv[tid] : 0.f;
  for (int r = 0; r < 8; ++r) { int idx = r*256 + tid; wrtL[idx>>6][idx&63] = wrt[idx]; }

  f32x4 asum[4];
  #pragma unroll
  for (int n = 0; n < 4; ++n) asum[n] = (f32x4){0.f,0.f,0.f,0.f};

  for (int tt = 0; tt < 8; ++tt) {
    int t = tc * 8 + tt;
    int base = b * 128 + t;
    __syncthreads();
    xs[tid >> 2][tid & 3] = x[base * 256 + tid];
    if (tid < 64) maskv[tid] = mask[base * 64 + tid];
    if (tid < 16) peL[tid] = PE[base * 16 + tid];
    __syncthreads();
    { // h (masked obs embedding) + catB build
      int e = tid & 63, s0 = (tid >> 6) * 16;
      #pragma unroll
      for (int si = 0; si < 16; ++si) {
        int s = s0 + si;
        float a = xs[s][0]*Wobs[(s*4+0)*64+e] + xs[s][1]*Wobs[(s*4+1)*64+e]
                + xs[s][2]*Wobs[(s*4+2)*64+e] + xs[s][3]*Wobs[(s*4+3)*64+e];
        a = fmaxf(a, 0.f) * maskv[s];
        hA[s][e] = f2bf(a);
      }
      for (int r = 0; r < 8; ++r) {
        int idx = r*256 + tid; int j = idx >> 5, d = idx & 31;
        float v = (d < 10) ? battn[j*10 + d] : ((d < 26) ? peL[d-10] : 0.f);
        catB[j][d] = f2bf(v);
      }
    }
    __syncthreads();
    { // h_map = h @ W_recv + b_recv (no relu)
      short8 a0 = *(const short8*)&hA[arow][kb];
      short8 a1 = *(const short8*)&hA[arow][32 + kb];
      #pragma unroll
      for (int n = 0; n < 2; ++n) {
        f32x4 acc = (f32x4){0.f,0.f,0.f,0.f};
        short8 b0 = *(const short8*)&wrtL[16*n + lr][kb];
        short8 b1 = *(const short8*)&wrtL[16*n + lr][32 + kb];
        acc = __builtin_amdgcn_mfma_f32_16x16x32_bf16(a0, b0, acc, 0, 0, 0);
        acc = __builtin_amdgcn_mfma_f32_16x16x32_bf16(a1, b1, acc, 0, 0, 0);
        int d = 16*n + lr;
        float bias = brecvL[d];
        #pragma unroll
        for (int reg = 0; reg < 4; ++reg) {
          int i = 16*w + lq*4 + reg;
          hmA[i][d] = f2bf(acc[reg] + bias);
        }
      }
    }
    __syncthreads();
    { // alpha = relu(h_map @ cat^T), accumulate
      short8 am = *(const short8*)&hmA[arow][kb];
      #pragma unroll
      for (int n = 0; n < 4; ++n) {
        f32x4 z = (f32x4){0.f,0.f,0.f,0.f};
        short8 bc = *(const short8*)&catB[16*n + lr][kb];
        z = __builtin_amdgcn_mfma_f32_16x16x32_bf16(am, bc, z, 0, 0, 0);
        #pragma unroll
        for (int reg = 0; reg < 4; ++reg) asum[n][reg] += fmaxf(z[reg], 0.f);
      }
    }
  }
  #pragma unroll
  for (int n = 0; n < 4; ++n) {
    #pragma unroll
    for (int reg = 0; reg < 4; ++reg) {
      int i = 16*w + lq*4 + reg, j = 16*n + lr;
      atomicAdd(&adj[((size_t)b << 12) + (i << 6) + j], asum[n][reg]);
    }
  }
}

// ---------------- K2: full per-(b,t) chain -> Hh bf16 ----------------
__global__ __launch_bounds__(256)
void k_main(const float* __restrict__ x, const float* __restrict__ mask,
            const float* __restrict__ Wobs, const float* __restrict__ battn,
            const float* __restrict__ brecv, const float* __restrict__ ws_f,
            const u16* __restrict__ wrt, u16* __restrict__ Hh) {
  __shared__ float xs[64][4];
  __shared__ float maskv[64];
  __shared__ float peL[16];
  __shared__ float brecvL[32];
  __shared__ float rmsL[64];
  __shared__ __align__(16) u16 wrtL[32][72];
  __shared__ __align__(16) u16 hA[64][72];    // h row-major; later reused as h1T
  __shared__ __align__(16) u16 hT[64][72];    // h transposed [e][s]
  __shared__ __align__(16) u16 hmA[64][40];
  __shared__ __align__(16) u16 catB[64][40];
  __shared__ __align__(16) u16 wA[64][72];    // w1 then w2

  const int tid = threadIdx.x;
  const int t = blockIdx.x, b = blockIdx.y;
  const int w = tid >> 6, l = tid & 63, lr = l & 15, lq = l >> 4, kb = lq * 8;
  const int arow = 16 * w + lr;
  const float* PE = ws_f + OFF_PE;
  const float* bidirG = ws_f + OFF_BIDIR;
  const float* adjG = ws_f + OFF_ADJ + (size_t)b * 4096;
  const int base = b * 128 + t;

  if (tid < 32) brecvL[tid] = (tid < 26) ? brecv[tid] : 0.f;
  if (tid < 64) rmsL[tid] = 1.f / (ws_f + OFF_MS)[b*64 + tid];
  for (int r = 0; r < 8; ++r) { int idx = r*256 + tid; wrtL[idx>>6][idx&63] = wrt[idx]; }
  xs[tid >> 2][tid & 3] = x[base * 256 + tid];
  if (tid < 64) maskv[tid] = mask[base * 64 + tid];
  if (tid < 16) peL[tid] = PE[base * 16 + tid];
  __syncthreads();

  { // h: store row-major and transposed
    int e = tid & 63, s0 = (tid >> 6) * 16;
    #pragma unroll
    for (int si = 0; si < 16; si += 2) {
      int s = s0 + si;
      float a0 = xs[s][0]*Wobs[(s*4+0)*64+e] + xs[s][1]*Wobs[(s*4+1)*64+e]
               + xs[s][2]*Wobs[(s*4+2)*64+e] + xs[s][3]*Wobs[(s*4+3)*64+e];
      a0 = fmaxf(a0, 0.f) * maskv[s];
      int s1 = s + 1;
      float a1 = xs[s1][0]*Wobs[(s1*4+0)*64+e] + xs[s1][1]*Wobs[(s1*4+1)*64+e]
               + xs[s1][2]*Wobs[(s1*4+2)*64+e] + xs[s1][3]*Wobs[(s1*4+3)*64+e];
      a1 = fmaxf(a1, 0.f) * maskv[s1];
      u16 b0 = f2bf(a0), b1 = f2bf(a1);
      hA[s][e] = b0; hA[s1][e] = b1;
      *(u32*)&hT[e][s] = (u32)b0 | ((u32)b1 << 16);
    }
    for (int r = 0; r < 8; ++r) {
      int idx = r*256 + tid; int j = idx >> 5, d = idx & 31;
      float v = (d < 10) ? battn[j*10 + d] : ((d < 26) ? peL[d-10] : 0.f);
      catB[j][d] = f2bf(v);
    }
  }
  __syncthreads();

  { // h_map
    short8 a0 = *(const short8*)&hA[arow][kb];
    short8 a1 = *(const short8*)&hA[arow][32 + kb];
    #pragma unroll
    for (int n = 0; n < 2; ++n) {
      f32x4 acc = (f32x4){0.f,0.f,0.f,0.f};
      short8 b0 = *(const short8*)&wrtL[16*n + lr][kb];
      short8 b1 = *(const short8*)&wrtL[16*n + lr][32 + kb];
      acc = __builtin_amdgcn_mfma_f32_16x16x32_bf16(a0, b0, acc, 0, 0, 0);
      acc = __builtin_amdgcn_mfma_f32_16x16x32_bf16(a1, b1, acc, 0, 0, 0);
      int d = 16*n + lr;
      float bias = brecvL[d];
      #pragma unroll
      for (int reg = 0; reg < 4; ++reg) {
        int i = 16*w + lq*4 + reg;
        hmA[i][d] = f2bf(acc[reg] + bias);
      }
    }
  }
  __syncthreads();

  f32x4 w2v[4];
  { // alpha -> w1 (store), w2 (keep in regs)
    short8 am = *(const short8*)&hmA[arow][kb];
    #pragma unroll
    for (int n = 0; n < 4; ++n) {
      f32x4 z = (f32x4){0.f,0.f,0.f,0.f};
      short8 bc = *(const short8*)&catB[16*n + lr][kb];
      z = __builtin_amdgcn_mfma_f32_16x16x32_bf16(am, bc, z, 0, 0, 0);
      #pragma unroll
      for (int reg = 0; reg < 4; ++reg) {
        int i = 16*w + lq*4 + reg, j = 16*n + lr;
        float al = fmaxf(z[reg], 0.f);
        float w1 = bidirG[(i << 6) + j] * al;
        wA[i][j] = f2bf(w1);
        w2v[n][reg] = w1 * (adjG[(i << 6) + j] * rmsL[i]);
      }
    }
  }
  __syncthreads();

  { // h1 = relu(w1 @ h)  -> h1T (reuse hA buffer)
    short8 aw0 = *(const short8*)&wA[arow][kb];
    short8 aw1 = *(const short8*)&wA[arow][32 + kb];
    #pragma unroll
    for (int n = 0; n < 4; ++n) {
      f32x4 acc = (f32x4){0.f,0.f,0.f,0.f};
      short8 b0 = *(const short8*)&hT[16*n + lr][kb];
      short8 b1 = *(const short8*)&hT[16*n + lr][32 + kb];
      acc = __builtin_amdgcn_mfma_f32_16x16x32_bf16(aw0, b0, acc, 0, 0, 0);
      acc = __builtin_amdgcn_mfma_f32_16x16x32_bf16(aw1, b1, acc, 0, 0, 0);
      int e = 16*n + lr, ib = 16*w + lq*4;
      u32 p0 = (u32)f2bf(fmaxf(acc[0],0.f)) | ((u32)f2bf(fmaxf(acc[1],0.f)) << 16);
      u32 p1 = (u32)f2bf(fmaxf(acc[2],0.f)) | ((u32)f2bf(fmaxf(acc[3],0.f)) << 16);
      uint2 pp; pp.x = p0; pp.y = p1;
      *(uint2*)&hA[e][ib] = pp;   // hA now holds h1T[e][i]
    }
  }
  __syncthreads();

  { // overwrite wA with w2
    #pragma unroll
    for (int n = 0; n < 4; ++n) {
      #pragma unroll
      for (int reg = 0; reg < 4; ++reg) {
        int i = 16*w + lq*4 + reg, j = 16*n + lr;
        wA[i][j] = f2bf(w2v[n][reg]);
      }
    }
  }
  __syncthreads();

  { // h2 = relu(w2 @ h1) -> global Hh bf16
    short8 a20 = *(const short8*)&wA[arow][kb];
    short8 a21 = *(const short8*)&wA[arow][32 + kb];
    size_t obase = ((size_t)b * 64) * 8192 + (size_t)t * 64;
    #pragma unroll
    for (int n = 0; n < 4; ++n) {
      f32x4 acc = (f32x4){0.f,0.f,0.f,0.f};
      short8 b0 = *(const short8*)&hA[16*n + lr][kb];      // h1T
      short8 b1 = *(const short8*)&hA[16*n + lr][32 + kb];
      acc = __builtin_amdgcn_mfma_f32_16x16x32_bf16(a20, b0, acc, 0, 0, 0);
      acc = __builtin_amdgcn_mfma_f32_16x16x32_bf16(a21, b1, acc, 0, 0, 0);
      int e = 16*n + lr;
      #pragma unroll
      for (int reg = 0; reg < 4; ++reg) {
        int i = 16*w + lq*4 + reg;
        Hh[obase + (size_t)i * 8192 + e] = f2bf(fmaxf(acc[reg], 0.f));
      }
    }
  }
}

// ---------------- K3: collapsed temporal attention ----------------
__global__ __launch_bounds__(256)
void k_attn(const float* __restrict__ ws_f, const u16* __restrict__ Hh,
            const float* __restrict__ Wq, const float* __restrict__ bq,
            const float* __restrict__ Wk, const float* __restrict__ bk,
            const float* __restrict__ Ws, const float* __restrict__ bs,
            const float* __restrict__ Wemb, const float* __restrict__ bemb,
            float* __restrict__ out) {
  __shared__ __align__(16) u16 Ht[128][72];
  __shared__ float peB[128][16];
  __shared__ float wsL[128];
  __shared__ float hbarL[80];
  __shared__ float KtilL[10];
  __shared__ float qvL[80];
  __shared__ float houtL[80];
  __shared__ float bb[128];
  __shared__ float red[8];
  __shared__ float cstL, sWL;

  const int tid = threadIdx.x;
  const int s = blockIdx.x, b = blockIdx.y;
  const float scale = 0.111803398875f; // 1/sqrt(80)

  const u16* src = Hh + ((size_t)b * 64 + s) * 8192;
  #pragma unroll
  for (int r = 0; r < 4; ++r) {
    int id = r * 256 + tid;
    int tt = id >> 3, c = (id & 7) * 8;
    *(uint4*)&Ht[tt][c] = *(const uint4*)&src[tt * 64 + c];
  }
  for (int r = 0; r < 8; ++r) {
    int id = r * 256 + tid;
    peB[id >> 4][id & 15] = ws_f[OFF_PE + (size_t)b * 2048 + id];
  }
  if (tid < 128) wsL[tid] = Ws[tid];
  __syncthreads();

  if (tid < 80) {
    float acc = 0.f;
    for (int t = 0; t < 128; ++t) {
      float hv = (tid < 64) ? bf2f(Ht[t][tid]) : peB[t][tid - 64];
      acc += wsL[t] * hv;
    }
    hbarL[tid] = acc;
  } else if (tid == 80) {
    float sw = 0.f;
    for (int t = 0; t < 128; ++t) sw += wsL[t];
    sWL = sw;
  }
  __syncthreads();
  if (tid < 10) {
    float acc = sWL * bk[tid];
    for (int d = 0; d < 80; ++d) acc += hbarL[d] * Wk[d*10 + tid];
    KtilL[tid] = acc;
  }
  __syncthreads();
  if (tid < 80) {
    float acc = 0.f;
    #pragma unroll
    for (int a = 0; a < 10; ++a) acc += Wq[tid*10 + a] * KtilL[a];
    qvL[tid] = acc;
  } else if (tid == 80) {
    float cq = 0.f;
    #pragma unroll
    for (int a = 0; a < 10; ++a) cq += bq[a] * KtilL[a];
    cstL = scale * cq + bs[0];
  }
  __syncthreads();
  if (tid < 128) {
    float acc = 0.f;
    #pragma unroll
    for (int c = 0; c < 8; ++c) {
      uint4 q = *(const uint4*)&Ht[tid][c*8];
      acc += bf2f((u16)(q.x & 0xFFFF)) * qvL[c*8+0] + bf2f((u16)(q.x >> 16)) * qvL[c*8+1];
      acc += bf2f((u16)(q.y & 0xFFFF)) * qvL[c*8+2] + bf2f((u16)(q.y >> 16)) * qvL[c*8+3];
      acc += bf2f((u16)(q.z & 0xFFFF)) * qvL[c*8+4] + bf2f((u16)(q.z >> 16)) * qvL[c*8+5];
      acc += bf2f((u16)(q.w & 0xFFFF)) * qvL[c*8+6] + bf2f((u16)(q.w >> 16)) * qvL[c*8+7];
    }
    #pragma unroll
    for (int k = 0; k < 16; ++k) acc += peB[tid][k] * qvL[64 + k];
    bb[tid] = scale * acc + cstL;
  }
  __syncthreads();
  float ev = 0.f;
  if (tid < 128) {
    float v = bb[tid], mm = v;
    #pragma unroll
    for (int off = 32; off; off >>= 1) mm = fmaxf(mm, __shfl_xor(mm, off));
    if ((tid & 63) == 0) red[tid >> 6] = mm;
  }
  __syncthreads();
  float m = fmaxf(red[0], red[1]);
  if (tid < 128) {
    ev = expf(bb[tid] - m);
    float ss = ev;
    #pragma unroll
    for (int off = 32; off; off >>= 1) ss += __shfl_xor(ss, off);
    if ((tid & 63) == 0) red[4 + (tid >> 6)] = ss;
  }
  __syncthreads();
  float denom = red[4] + red[5];
  if (tid < 128) bb[tid] = ev / denom;
  __syncthreads();
  if (tid < 80) {
    float acc = 0.f;
    for (int t = 0; t < 128; ++t) {
      float hv = (tid < 64) ? bf2f(Ht[t][tid]) : peB[t][tid - 64];
      acc += bb[t] * hv;
    }
    houtL[tid] = acc;
  }
  __syncthreads();
  if (tid < 128) {
    float acc = bemb[tid];
    for (int d = 0; d < 80; ++d) acc += houtL[d] * Wemb[d*128 + tid];
    out[(((size_t)b * 64 + s) << 7) + tid] = acc;
  }
}

extern "C" void kernel_launch(void* const* d_in, const int* in_sizes, int n_in,
                              void* d_out, int out_size, void* d_ws, size_t ws_size,
                              hipStream_t stream) {
  (void)in_sizes; (void)n_in; (void)out_size; (void)ws_size;
  const float* x     = (const float*)d_in[0];
  const float* times = (const float*)d_in[1];
  const float* mask  = (const float*)d_in[2];
  const float* Wobs  = (const float*)d_in[3];
  const float* Wattn = (const float*)d_in[4];
  const float* Wrecv = (const float*)d_in[5];
  const float* brecv = (const float*)d_in[6];
  const float* Wb    = (const float*)d_in[7];
  const float* Wq    = (const float*)d_in[8];
  const float* bq    = (const float*)d_in[9];
  const float* Wk    = (const float*)d_in[10];
  const float* bk    = (const float*)d_in[11];
  const float* Ws    = (const float*)d_in[12];
  const float* bs    = (const float*)d_in[13];
  const float* Wemb  = (const float*)d_in[14];
  const float* bemb  = (const float*)d_in[15];
  float* out = (float*)d_out;
  float* ws_f = (float*)d_ws;
  u16* wrt = (u16*)((char*)d_ws + BOFF_WRT);
  u16* Hh  = (u16*)((char*)d_ws + BOFF_HH);

  hipMemsetAsync((char*)d_ws + (size_t)OFF_ADJ * 4, 0, (size_t)64 * 64 * 64 * 4, stream);
  k_pre<<<98, 256, 0, stream>>>(times, mask, Wb, Wrecv, ws_f, wrt);
  k_adj<<<dim3(16, 64), 256, 0, stream>>>(x, mask, Wobs, Wattn, brecv, ws_f, wrt);
  k_main<<<dim3(128, 64), 256, 0, stream>>>(x, mask, Wobs, Wattn, brecv, ws_f, wrt, Hh);
  k_attn<<<dim3(64, 64), 256, 0, stream>>>(ws_f, Hh, Wq, bq, Wk, bk, Ws, bs, Wemb, bemb, out);
}

// Round 2
// 232.973 us; speedup vs baseline: 1.1878x; 1.1878x over previous
//
#include <hip/hip_runtime.h>
#include <hip/hip_bf16.h>

// Raindrop forward, MI355X. B=64 T=128 S=64 O=4 E=64 P=16 A=10 OUT=128.
//  - temporal attention collapsed: (Q K^T) W_s = Q (W_s^T K)  -> no TxT matrix
//  - heavy per-(b,t) matmuls (h_map, alpha, 2x propagate) in bf16 MFMA 16x16x32
//  - k_attn: chunked cross-thread reductions, odd-dword LDS pitches
// ws layout (floats): PE[B*T*16] | bidir[64*64] | masksum[B*64] | adj2num[B*64*64]
// then bytes: WrT bf16 [32][64] | Hh bf16 [B][S][T][64]

typedef unsigned short u16;
typedef unsigned int u32;
typedef __attribute__((ext_vector_type(8))) short short8;
typedef __attribute__((ext_vector_type(4))) float f32x4;

#define OFF_PE    0
#define OFF_BIDIR 131072
#define OFF_MS    135168
#define OFF_ADJ   139264
#define BOFF_WRT  4751360u
#define BOFF_HH   4755456u

__device__ __forceinline__ u16 f2bf(float f){
  __hip_bfloat16 h = __float2bfloat16(f);
  union { __hip_bfloat16 h; u16 u; } v; v.h = h; return v.u;
}
__device__ __forceinline__ u32 pk2bf(float lo, float hi){
  __hip_bfloat162 h = __float22bfloat162_rn(float2{lo, hi});
  union { __hip_bfloat162 h; u32 u; } v; v.h = h; return v.u;
}
__device__ __forceinline__ float bf2f(u16 h){
  union { u32 u; float f; } v; v.u = ((u32)h) << 16; return v.f;
}

// ---------------- K0: PE table, bidir, WrT bf16, masksum ----------------
__global__ void k_pre(const float* __restrict__ times, const float* __restrict__ mask,
                      const float* __restrict__ Wb, const float* __restrict__ Wrecv,
                      float* __restrict__ ws_f, u16* __restrict__ wrt) {
  const int blk = blockIdx.x, tid = threadIdx.x;
  if (blk < 32) {                      // PE: (B*T,16) sin|cos
    float* PE = ws_f + OFF_PE;
    #pragma unroll
    for (int r = 0; r < 16; ++r) {
      int id = blk * 4096 + r * 256 + tid;
      int bt = id >> 4, k = id & 15;
      float tv = times[bt];
      int kk = k & 7;
      float fr = expf(-(float)kk * 1.1512925465f); // ln(1e4)/8
      float ang = tv * fr;
      PE[id] = (k < 8) ? sinf(ang) : cosf(ang);
    }
  } else if (blk == 32) {              // bidir = Wb @ Wb^T
    float* bidir = ws_f + OFF_BIDIR;
    for (int r = 0; r < 16; ++r) {
      int idx = r * 256 + tid;
      int i = idx >> 6, j = idx & 63;
      float acc = 0.f;
      for (int e = 0; e < 64; ++e) acc += Wb[i*64+e] * Wb[j*64+e];
      bidir[idx] = acc;
    }
  } else if (blk == 33) {              // WrT[d][e] = W_recv[e][d], pad d 26..31 = 0
    for (int r = 0; r < 8; ++r) {
      int idx = r * 256 + tid;
      int d = idx >> 6, e = idx & 63;
      wrt[idx] = (d < 26) ? f2bf(Wrecv[e*26 + d]) : (u16)0;
    }
  } else {                             // masksum[b][i] = sum_t mask
    int b = blk - 34;
    if (tid < 64) {
      float s = 0.f;
      for (int t = 0; t < 128; ++t) s += mask[(b*128 + t)*64 + tid];
      (ws_f + OFF_MS)[b*64 + tid] = s;
    }
  }
}

// ---------------- K1: adj2 numerator (sum_t alpha) ----------------
__global__ __launch_bounds__(256)
void k_adj(const float* __restrict__ x, const float* __restrict__ mask,
           const float* __restrict__ Wobs, const float* __restrict__ battn,
           const float* __restrict__ brecv, float* __restrict__ ws_f,
           const u16* __restrict__ wrt) {
  __shared__ float xs[64][4];
  __shared__ float maskv[64];
  __shared__ float peL[16];
  __shared__ float brecvL[32];
  __shared__ __align__(16) u16 hA[64][72];
  __shared__ __align__(16) u16 hmA[64][40];
  __shared__ __align__(16) u16 catB[64][40];
  __shared__ __align__(16) u16 wrtL[32][72];

  const int tid = threadIdx.x;
  const int b = blockIdx.y, tc = blockIdx.x;
  const int w = tid >> 6, l = tid & 63, lr = l & 15, lq = l >> 4, kb = lq * 8;
  const int arow = 16 * w + lr;
  const float* PE = ws_f + OFF_PE;
  float* adj = ws_f + OFF_ADJ;

  if (tid < 32) brecvL[tid] = (tid < 26) ? brecv[tid] : 0.f;
  for (int r = 0; r < 8; ++r) { int idx = r*256 + tid; wrtL[idx>>6][idx&63] = wrt[idx]; }

  f32x4 asum[4];
  #pragma unroll
  for (int n = 0; n < 4; ++n) asum[n] = (f32x4){0.f,0.f,0.f,0.f};

  for (int tt = 0; tt < 8; ++tt) {
    int t = tc * 8 + tt;
    int base = b * 128 + t;
    __syncthreads();
    xs[tid >> 2][tid & 3] = x[base * 256 + tid];
    if (tid < 64) maskv[tid] = mask[base * 64 + tid];
    if (tid < 16) peL[tid] = PE[base * 16 + tid];
    __syncthreads();
    { // h (masked obs embedding) + catB build
      int e = tid & 63, s0 = (tid >> 6) * 16;
      #pragma unroll
      for (int si = 0; si < 16; si += 2) {
        int s = s0 + si, s1 = s + 1;
        float a0 = xs[s][0]*Wobs[(s*4+0)*64+e] + xs[s][1]*Wobs[(s*4+1)*64+e]
                 + xs[s][2]*Wobs[(s*4+2)*64+e] + xs[s][3]*Wobs[(s*4+3)*64+e];
        a0 = fmaxf(a0, 0.f) * maskv[s];
        float a1 = xs[s1][0]*Wobs[(s1*4+0)*64+e] + xs[s1][1]*Wobs[(s1*4+1)*64+e]
                 + xs[s1][2]*Wobs[(s1*4+2)*64+e] + xs[s1][3]*Wobs[(s1*4+3)*64+e];
        a1 = fmaxf(a1, 0.f) * maskv[s1];
        u32 p = pk2bf(a0, a1);
        hA[s][e] = (u16)p; hA[s1][e] = (u16)(p >> 16);
      }
      for (int r = 0; r < 8; ++r) {
        int idx = r*256 + tid; int j = idx >> 5, d = idx & 31;
        float v = (d < 10) ? battn[j*10 + d] : ((d < 26) ? peL[d-10] : 0.f);
        catB[j][d] = f2bf(v);
      }
    }
    __syncthreads();
    { // h_map = h @ W_recv + b_recv (no relu)
      short8 a0 = *(const short8*)&hA[arow][kb];
      short8 a1 = *(const short8*)&hA[arow][32 + kb];
      #pragma unroll
      for (int n = 0; n < 2; ++n) {
        f32x4 acc = (f32x4){0.f,0.f,0.f,0.f};
        short8 b0 = *(const short8*)&wrtL[16*n + lr][kb];
        short8 b1 = *(const short8*)&wrtL[16*n + lr][32 + kb];
        acc = __builtin_amdgcn_mfma_f32_16x16x32_bf16(a0, b0, acc, 0, 0, 0);
        acc = __builtin_amdgcn_mfma_f32_16x16x32_bf16(a1, b1, acc, 0, 0, 0);
        int d = 16*n + lr;
        float bias = brecvL[d];
        int i0 = 16*w + lq*4;
        u32 p0 = pk2bf(acc[0] + bias, acc[1] + bias);
        u32 p1 = pk2bf(acc[2] + bias, acc[3] + bias);
        hmA[i0+0][d] = (u16)p0; hmA[i0+1][d] = (u16)(p0 >> 16);
        hmA[i0+2][d] = (u16)p1; hmA[i0+3][d] = (u16)(p1 >> 16);
      }
    }
    __syncthreads();
    { // alpha = relu(h_map @ cat^T), accumulate
      short8 am = *(const short8*)&hmA[arow][kb];
      #pragma unroll
      for (int n = 0; n < 4; ++n) {
        f32x4 z = (f32x4){0.f,0.f,0.f,0.f};
        short8 bc = *(const short8*)&catB[16*n + lr][kb];
        z = __builtin_amdgcn_mfma_f32_16x16x32_bf16(am, bc, z, 0, 0, 0);
        #pragma unroll
        for (int reg = 0; reg < 4; ++reg) asum[n][reg] += fmaxf(z[reg], 0.f);
      }
    }
  }
  #pragma unroll
  for (int n = 0; n < 4; ++n) {
    #pragma unroll
    for (int reg = 0; reg < 4; ++reg) {
      int i = 16*w + lq*4 + reg, j = 16*n + lr;
      atomicAdd(&adj[((size_t)b << 12) + (i << 6) + j], asum[n][reg]);
    }
  }
}

// ---------------- K2: full per-(b,t) chain -> Hh bf16 ----------------
__global__ __launch_bounds__(256)
void k_main(const float* __restrict__ x, const float* __restrict__ mask,
            const float* __restrict__ Wobs, const float* __restrict__ battn,
            const float* __restrict__ brecv, const float* __restrict__ ws_f,
            const u16* __restrict__ wrt, u16* __restrict__ Hh) {
  __shared__ float xs[64][4];
  __shared__ float maskv[64];
  __shared__ float peL[16];
  __shared__ float brecvL[32];
  __shared__ float rmsL[64];
  __shared__ __align__(16) u16 wrtL[32][72];
  __shared__ __align__(16) u16 hA[64][72];    // h row-major; later reused as h1T
  __shared__ __align__(16) u16 hT[64][72];    // h transposed [e][s]
  __shared__ __align__(16) u16 hmA[64][40];
  __shared__ __align__(16) u16 catB[64][40];
  __shared__ __align__(16) u16 wA[64][72];    // w1
  __shared__ __align__(16) u16 w2A[64][72];   // w2

  const int tid = threadIdx.x;
  const int t = blockIdx.x, b = blockIdx.y;
  const int w = tid >> 6, l = tid & 63, lr = l & 15, lq = l >> 4, kb = lq * 8;
  const int arow = 16 * w + lr;
  const float* PE = ws_f + OFF_PE;
  const float* bidirG = ws_f + OFF_BIDIR;
  const float* adjG = ws_f + OFF_ADJ + (size_t)b * 4096;
  const int base = b * 128 + t;

  if (tid < 32) brecvL[tid] = (tid < 26) ? brecv[tid] : 0.f;
  if (tid < 64) rmsL[tid] = 1.f / (ws_f + OFF_MS)[b*64 + tid];
  for (int r = 0; r < 8; ++r) { int idx = r*256 + tid; wrtL[idx>>6][idx&63] = wrt[idx]; }
  xs[tid >> 2][tid & 3] = x[base * 256 + tid];
  if (tid < 64) maskv[tid] = mask[base * 64 + tid];
  if (tid < 16) peL[tid] = PE[base * 16 + tid];
  __syncthreads();

  { // h: store row-major and transposed
    int e = tid & 63, s0 = (tid >> 6) * 16;
    #pragma unroll
    for (int si = 0; si < 16; si += 2) {
      int s = s0 + si, s1 = s + 1;
      float a0 = xs[s][0]*Wobs[(s*4+0)*64+e] + xs[s][1]*Wobs[(s*4+1)*64+e]
               + xs[s][2]*Wobs[(s*4+2)*64+e] + xs[s][3]*Wobs[(s*4+3)*64+e];
      a0 = fmaxf(a0, 0.f) * maskv[s];
      float a1 = xs[s1][0]*Wobs[(s1*4+0)*64+e] + xs[s1][1]*Wobs[(s1*4+1)*64+e]
               + xs[s1][2]*Wobs[(s1*4+2)*64+e] + xs[s1][3]*Wobs[(s1*4+3)*64+e];
      a1 = fmaxf(a1, 0.f) * maskv[s1];
      u32 p = pk2bf(a0, a1);
      hA[s][e] = (u16)p; hA[s1][e] = (u16)(p >> 16);
      *(u32*)&hT[e][s] = p;
    }
    for (int r = 0; r < 8; ++r) {
      int idx = r*256 + tid; int j = idx >> 5, d = idx & 31;
      float v = (d < 10) ? battn[j*10 + d] : ((d < 26) ? peL[d-10] : 0.f);
      catB[j][d] = f2bf(v);
    }
  }
  __syncthreads();

  { // h_map
    short8 a0 = *(const short8*)&hA[arow][kb];
    short8 a1 = *(const short8*)&hA[arow][32 + kb];
    #pragma unroll
    for (int n = 0; n < 2; ++n) {
      f32x4 acc = (f32x4){0.f,0.f,0.f,0.f};
      short8 b0 = *(const short8*)&wrtL[16*n + lr][kb];
      short8 b1 = *(const short8*)&wrtL[16*n + lr][32 + kb];
      acc = __builtin_amdgcn_mfma_f32_16x16x32_bf16(a0, b0, acc, 0, 0, 0);
      acc = __builtin_amdgcn_mfma_f32_16x16x32_bf16(a1, b1, acc, 0, 0, 0);
      int d = 16*n + lr;
      float bias = brecvL[d];
      int i0 = 16*w + lq*4;
      u32 p0 = pk2bf(acc[0] + bias, acc[1] + bias);
      u32 p1 = pk2bf(acc[2] + bias, acc[3] + bias);
      hmA[i0+0][d] = (u16)p0; hmA[i0+1][d] = (u16)(p0 >> 16);
      hmA[i0+2][d] = (u16)p1; hmA[i0+3][d] = (u16)(p1 >> 16);
    }
  }
  __syncthreads();

  { // alpha -> w1 (wA), w2 (w2A)
    short8 am = *(const short8*)&hmA[arow][kb];
    #pragma unroll
    for (int n = 0; n < 4; ++n) {
      f32x4 z = (f32x4){0.f,0.f,0.f,0.f};
      short8 bc = *(const short8*)&catB[16*n + lr][kb];
      z = __builtin_amdgcn_mfma_f32_16x16x32_bf16(am, bc, z, 0, 0, 0);
      int j = 16*n + lr;
      float w1v[4], w2v[4];
      #pragma unroll
      for (int reg = 0; reg < 4; ++reg) {
        int i = 16*w + lq*4 + reg;
        float al = fmaxf(z[reg], 0.f);
        float w1 = bidirG[(i << 6) + j] * al;
        w1v[reg] = w1;
        w2v[reg] = w1 * (adjG[(i << 6) + j] * rmsL[i]);
      }
      int i0 = 16*w + lq*4;
      u32 p0 = pk2bf(w1v[0], w1v[1]), p1 = pk2bf(w1v[2], w1v[3]);
      wA[i0+0][j] = (u16)p0; wA[i0+1][j] = (u16)(p0 >> 16);
      wA[i0+2][j] = (u16)p1; wA[i0+3][j] = (u16)(p1 >> 16);
      u32 q0 = pk2bf(w2v[0], w2v[1]), q1 = pk2bf(w2v[2], w2v[3]);
      w2A[i0+0][j] = (u16)q0; w2A[i0+1][j] = (u16)(q0 >> 16);
      w2A[i0+2][j] = (u16)q1; w2A[i0+3][j] = (u16)(q1 >> 16);
    }
  }
  __syncthreads();

  { // h1 = relu(w1 @ h)  -> h1T (reuse hA buffer)
    short8 aw0 = *(const short8*)&wA[arow][kb];
    short8 aw1 = *(const short8*)&wA[arow][32 + kb];
    #pragma unroll
    for (int n = 0; n < 4; ++n) {
      f32x4 acc = (f32x4){0.f,0.f,0.f,0.f};
      short8 b0 = *(const short8*)&hT[16*n + lr][kb];
      short8 b1 = *(const short8*)&hT[16*n + lr][32 + kb];
      acc = __builtin_amdgcn_mfma_f32_16x16x32_bf16(aw0, b0, acc, 0, 0, 0);
      acc = __builtin_amdgcn_mfma_f32_16x16x32_bf16(aw1, b1, acc, 0, 0, 0);
      int e = 16*n + lr, ib = 16*w + lq*4;
      uint2 pp;
      pp.x = pk2bf(fmaxf(acc[0],0.f), fmaxf(acc[1],0.f));
      pp.y = pk2bf(fmaxf(acc[2],0.f), fmaxf(acc[3],0.f));
      *(uint2*)&hA[e][ib] = pp;   // hA now holds h1T[e][i]
    }
  }
  __syncthreads();

  { // h2 = relu(w2 @ h1) -> global Hh bf16
    short8 a20 = *(const short8*)&w2A[arow][kb];
    short8 a21 = *(const short8*)&w2A[arow][32 + kb];
    size_t obase = ((size_t)b * 64) * 8192 + (size_t)t * 64;
    #pragma unroll
    for (int n = 0; n < 4; ++n) {
      f32x4 acc = (f32x4){0.f,0.f,0.f,0.f};
      short8 b0 = *(const short8*)&hA[16*n + lr][kb];      // h1T
      short8 b1 = *(const short8*)&hA[16*n + lr][32 + kb];
      acc = __builtin_amdgcn_mfma_f32_16x16x32_bf16(a20, b0, acc, 0, 0, 0);
      acc = __builtin_amdgcn_mfma_f32_16x16x32_bf16(a21, b1, acc, 0, 0, 0);
      int e = 16*n + lr, i0 = 16*w + lq*4;
      u32 p0 = pk2bf(fmaxf(acc[0],0.f), fmaxf(acc[1],0.f));
      u32 p1 = pk2bf(fmaxf(acc[2],0.f), fmaxf(acc[3],0.f));
      Hh[obase + (size_t)(i0+0) * 8192 + e] = (u16)p0;
      Hh[obase + (size_t)(i0+1) * 8192 + e] = (u16)(p0 >> 16);
      Hh[obase + (size_t)(i0+2) * 8192 + e] = (u16)p1;
      Hh[obase + (size_t)(i0+3) * 8192 + e] = (u16)(p1 >> 16);
    }
  }
}

// ---------------- K3: collapsed temporal attention ----------------
#define HTP 82   // odd-dword pitch (u16): row stride 164B -> conflict-free column walks
#define PEP 17   // odd-dword pitch (f32)

__global__ __launch_bounds__(256)
void k_attn(const float* __restrict__ ws_f, const u16* __restrict__ Hh,
            const float* __restrict__ Wq, const float* __restrict__ bq,
            const float* __restrict__ Wk, const float* __restrict__ bk,
            const float* __restrict__ Ws, const float* __restrict__ bs,
            const float* __restrict__ Wemb, const float* __restrict__ bemb,
            float* __restrict__ out) {
  __shared__ u16 Ht[128][HTP];
  __shared__ float peB[128][PEP];
  __shared__ float wsL[128];
  __shared__ float pA[3][80];      // hbar partials; reused for hout partials
  __shared__ float pK[8][10];
  __shared__ float KtilL[10];
  __shared__ float qvL[80];
  __shared__ float pC[2][128];     // beta partials; reused for out partials
  __shared__ float bb[128];
  __shared__ float red[4];
  __shared__ float cstL, sWL;

  const int tid = threadIdx.x;
  const int s = blockIdx.x, b = blockIdx.y;
  const float scale = 0.111803398875f; // 1/sqrt(80)

  const u16* src = Hh + ((size_t)b * 64 + s) * 8192;
  #pragma unroll
  for (int r = 0; r < 4; ++r) {
    int id = r * 256 + tid;
    int tt = id >> 3, c = (id & 7) * 8;
    uint4 q = *(const uint4*)&src[tt * 64 + c];
    u32* dst = (u32*)&Ht[tt][c];
    dst[0] = q.x; dst[1] = q.y; dst[2] = q.z; dst[3] = q.w;
  }
  #pragma unroll
  for (int r = 0; r < 8; ++r) {
    int id = r * 256 + tid;
    peB[id >> 4][id & 15] = ws_f[OFF_PE + (size_t)b * 2048 + id];
  }
  if (tid < 128) wsL[tid] = Ws[tid];
  __syncthreads();

  // Phase A: pA[c][d] = sum_{t in chunk c} ws[t]*H[t][d]  (3 chunks of ~43)
  if (tid < 240) {
    int d = tid % 80, c = tid / 80;
    int t0 = c * 43, t1 = (c == 2) ? 128 : t0 + 43;
    float acc = 0.f;
    if (d < 64) {
      for (int t = t0; t < t1; ++t) acc += wsL[t] * bf2f(Ht[t][d]);
    } else {
      int k = d - 64;
      for (int t = t0; t < t1; ++t) acc += wsL[t] * peB[t][k];
    }
    pA[c][d] = acc;
  } else if (tid == 240) {
    float sw = 0.f;
    for (int t = 0; t < 128; ++t) sw += wsL[t];
    sWL = sw;
  }
  __syncthreads();

  // Ktil partials: pK[c][a] = sum_{d in chunk} hbar[d]*Wk[d*10+a]
  if (tid < 80) {
    int a = tid % 10, c = tid / 10;
    float acc = 0.f;
    #pragma unroll
    for (int i = 0; i < 10; ++i) {
      int d = c * 10 + i;
      float hb = pA[0][d] + pA[1][d] + pA[2][d];
      acc += hb * Wk[d * 10 + a];
    }
    pK[c][a] = acc;
  }
  __syncthreads();
  if (tid < 10) {
    float acc = sWL * bk[tid];
    #pragma unroll
    for (int c = 0; c < 8; ++c) acc += pK[c][tid];
    KtilL[tid] = acc;
  }
  __syncthreads();
  if (tid < 80) {
    float acc = 0.f;
    #pragma unroll
    for (int a = 0; a < 10; ++a) acc += Wq[tid * 10 + a] * KtilL[a];
    qvL[tid] = acc;
  } else if (tid == 80) {
    float cq = 0.f;
    #pragma unroll
    for (int a = 0; a < 10; ++a) cq += bq[a] * KtilL[a];
    cstL = scale * cq + bs[0];
  }
  __syncthreads();

  // Phase C: beta partials over d-halves
  {
    int t = tid & 127, half = tid >> 7;
    float acc = 0.f;
    const u32* row = (const u32*)&Ht[t][0];
    if (half == 0) {
      #pragma unroll
      for (int i = 0; i < 20; ++i) {
        u32 p = row[i];
        acc += bf2f((u16)p) * qvL[2*i] + bf2f((u16)(p >> 16)) * qvL[2*i+1];
      }
    } else {
      #pragma unroll
      for (int i = 20; i < 32; ++i) {
        u32 p = row[i];
        acc += bf2f((u16)p) * qvL[2*i] + bf2f((u16)(p >> 16)) * qvL[2*i+1];
      }
      #pragma unroll
      for (int k = 0; k < 16; ++k) acc += peB[t][k] * qvL[64 + k];
    }
    pC[half][t] = acc;
  }
  __syncthreads();

  // softmax over t
  float ev = 0.f;
  if (tid < 128) {
    float v = scale * (pC[0][tid] + pC[1][tid]) + cstL;
    bb[tid] = v;
    float mm = v;
    #pragma unroll
    for (int off = 32; off; off >>= 1) mm = fmaxf(mm, __shfl_xor(mm, off));
    if ((tid & 63) == 0) red[tid >> 6] = mm;
  }
  __syncthreads();
  float m = fmaxf(red[0], red[1]);
  if (tid < 128) {
    ev = expf(bb[tid] - m);
    float ss = ev;
    #pragma unroll
    for (int off = 32; off; off >>= 1) ss += __shfl_xor(ss, off);
    if ((tid & 63) == 0) red[2 + (tid >> 6)] = ss;
  }
  __syncthreads();
  if (tid < 128) bb[tid] = ev / (red[2] + red[3]);
  __syncthreads();

  // Phase E: hout partials (reuse pA)
  if (tid < 240) {
    int d = tid % 80, c = tid / 80;
    int t0 = c * 43, t1 = (c == 2) ? 128 : t0 + 43;
    float acc = 0.f;
    if (d < 64) {
      for (int t = t0; t < t1; ++t) acc += bb[t] * bf2f(Ht[t][d]);
    } else {
      int k = d - 64;
      for (int t = t0; t < t1; ++t) acc += bb[t] * peB[t][k];
    }
    pA[c][d] = acc;
  }
  __syncthreads();

  // Phase F: out partials over d-halves (reuse pC)
  {
    int o = tid & 127, half = tid >> 7;
    int d0 = half * 40;
    float acc = 0.f;
    #pragma unroll
    for (int i = 0; i < 40; ++i) {
      int d = d0 + i;
      float hv = pA[0][d] + pA[1][d] + pA[2][d];
      acc += hv * Wemb[d * 128 + o];
    }
    pC[half][o] = acc;
  }
  __syncthreads();
  if (tid < 128) {
    out[(((size_t)b * 64 + s) << 7) + tid] = bemb[tid] + pC[0][tid] + pC[1][tid];
  }
}

extern "C" void kernel_launch(void* const* d_in, const int* in_sizes, int n_in,
                              void* d_out, int out_size, void* d_ws, size_t ws_size,
                              hipStream_t stream) {
  (void)in_sizes; (void)n_in; (void)out_size; (void)ws_size;
  const float* x     = (const float*)d_in[0];
  const float* times = (const float*)d_in[1];
  const float* mask  = (const float*)d_in[2];
  const float* Wobs  = (const float*)d_in[3];
  const float* Wattn = (const float*)d_in[4];
  const float* Wrecv = (const float*)d_in[5];
  const float* brecv = (const float*)d_in[6];
  const float* Wb    = (const float*)d_in[7];
  const float* Wq    = (const float*)d_in[8];
  const float* bq    = (const float*)d_in[9];
  const float* Wk    = (const float*)d_in[10];
  const float* bk    = (const float*)d_in[11];
  const float* Ws    = (const float*)d_in[12];
  const float* bs    = (const float*)d_in[13];
  const float* Wemb  = (const float*)d_in[14];
  const float* bemb  = (const float*)d_in[15];
  float* out = (float*)d_out;
  float* ws_f = (float*)d_ws;
  u16* wrt = (u16*)((char*)d_ws + BOFF_WRT);
  u16* Hh  = (u16*)((char*)d_ws + BOFF_HH);

  hipMemsetAsync((char*)d_ws + (size_t)OFF_ADJ * 4, 0, (size_t)64 * 64 * 64 * 4, stream);
  k_pre<<<98, 256, 0, stream>>>(times, mask, Wb, Wrecv, ws_f, wrt);
  k_adj<<<dim3(16, 64), 256, 0, stream>>>(x, mask, Wobs, Wattn, brecv, ws_f, wrt);
  k_main<<<dim3(128, 64), 256, 0, stream>>>(x, mask, Wobs, Wattn, brecv, ws_f, wrt, Hh);
  k_attn<<<dim3(64, 64), 256, 0, stream>>>(ws_f, Hh, Wq, bq, Wk, bk, Ws, bs, Wemb, bemb, out);
}